// Round 1
// baseline (1729.607 us; speedup 1.0000x reference)
//
#include <hip/hip_runtime.h>

// Problem constants
#define N_    64
#define CIN   192
#define COUT  192
#define H_    64
#define W_    64
#define HW    4096                  // H*W
#define M_    262144.0f             // N*H*W (BN reduction count)
#define BN_EPS 1e-5f

// ---------------------------------------------------------------------------
// Kernel 0: zero the BN accumulators (ws is poisoned 0xAA before every call)
// ws layout (floats): [0..191]=sum  [192..383]=sumsq  [384..575]=scale [576..767]=shift
// ---------------------------------------------------------------------------
__global__ __launch_bounds__(384) void zero_ws(float* __restrict__ ws) {
    int t = threadIdx.x;
    if (t < 384) ws[t] = 0.f;
}

// ---------------------------------------------------------------------------
// Kernel 1: fused ReLU + depthwise dilated conv + pointwise GEMM + BN stats
// One block per (n, h) output row. Block = 256 threads.
//  Phase 1: y_tile[c][w] = sum_{dh,dw} relu(x[n,c,h+2dh-2,w+2dw-2]) * dw_w[c,dh,dw]
//  Phase 2: z[o][w] = sum_k pw[o][k] * y_tile[k][w]   (12x4 microtile/thread)
//  Stores z to zout, atomically accumulates per-channel sum / sumsq.
// ---------------------------------------------------------------------------
__global__ __launch_bounds__(256, 2) void fused_kernel(
    const float* __restrict__ x, const float* __restrict__ dww,
    const float* __restrict__ pw, float* __restrict__ zout,
    float* __restrict__ ws)
{
    __shared__ float sdw[CIN * 9];          //  6.9 KB depthwise weights
    __shared__ float sy[CIN * W_];          // 48 KB y tile [192][64]

    const int t = threadIdx.x;
    const int n = blockIdx.x >> 6;          // H_=64 rows per image
    const int h = blockIdx.x & 63;

    for (int i = t; i < CIN * 9; i += 256) sdw[i] = dww[i];

    // ---- Phase 1: depthwise ----
    const int  w   = t & 63;                // each wave covers w = 0..63
    const int  c0  = t >> 6;                // 0..3
    const bool wm0 = (w >= 2);
    const bool wm2 = (w <= 61);
    const int  om  = wm0 ? -2 : 0;          // clamped tap offsets (avoid OOB)
    const int  op  = wm2 ?  2 : 0;
    __syncthreads();

    #pragma unroll 4
    for (int e = 0; e < 48; ++e) {
        const int c = c0 + (e << 2);
        const float* xr0 = x + ((((size_t)n * CIN + c) << 12)) + w;
        const float* kw  = &sdw[c * 9];
        float acc = 0.f;
        #pragma unroll
        for (int dh = 0; dh < 3; ++dh) {
            const int hh = h + 2 * dh - 2;
            if ((unsigned)hh < 64u) {       // uniform branch per block
                const float* xr = xr0 + (hh << 6);
                float v0 = fmaxf(xr[om], 0.f);
                float v1 = fmaxf(xr[0],  0.f);
                float v2 = fmaxf(xr[op], 0.f);
                v0 = wm0 ? v0 : 0.f;
                v2 = wm2 ? v2 : 0.f;
                acc = fmaf(v0, kw[3 * dh + 0], acc);
                acc = fmaf(v1, kw[3 * dh + 1], acc);
                acc = fmaf(v2, kw[3 * dh + 2], acc);
            }
        }
        sy[(c << 6) + w] = acc;
    }
    __syncthreads();

    // ---- Phase 2: pointwise GEMM ----
    const int ot = t >> 4;                  // 0..15 -> o tile of 12
    const int wt = t & 15;                  // 0..15 -> w tile of 4 (float4)
    const int o0 = ot * 12;

    float acc[12][4];
    #pragma unroll
    for (int i = 0; i < 12; ++i)
        #pragma unroll
        for (int j = 0; j < 4; ++j) acc[i][j] = 0.f;

    const float4* sy4 = (const float4*)sy;

#define FMA4(WC, Y)                              \
    acc[i][0] = fmaf(WC, (Y).x, acc[i][0]);      \
    acc[i][1] = fmaf(WC, (Y).y, acc[i][1]);      \
    acc[i][2] = fmaf(WC, (Y).z, acc[i][2]);      \
    acc[i][3] = fmaf(WC, (Y).w, acc[i][3]);

    for (int k = 0; k < CIN; k += 4) {
        const float4 y0 = sy4[((k + 0) << 4) + wt];
        const float4 y1 = sy4[((k + 1) << 4) + wt];
        const float4 y2 = sy4[((k + 2) << 4) + wt];
        const float4 y3 = sy4[((k + 3) << 4) + wt];
        #pragma unroll
        for (int i = 0; i < 12; ++i) {
            const float4 wv = *(const float4*)(pw + (size_t)(o0 + i) * CIN + k);
            FMA4(wv.x, y0)
            FMA4(wv.y, y1)
            FMA4(wv.z, y2)
            FMA4(wv.w, y3)
        }
    }
#undef FMA4

    // ---- Store z + BN stat accumulation ----
    const size_t obase = (((size_t)n * COUT) << 12) + ((size_t)h << 6) + (wt << 2);
    #pragma unroll
    for (int i = 0; i < 12; ++i) {
        const int o = o0 + i;
        float4 st;
        st.x = acc[i][0]; st.y = acc[i][1]; st.z = acc[i][2]; st.w = acc[i][3];
        *(float4*)(zout + obase + ((size_t)o << 12)) = st;

        float s  = acc[i][0] + acc[i][1] + acc[i][2] + acc[i][3];
        float ss = acc[i][0] * acc[i][0] + acc[i][1] * acc[i][1]
                 + acc[i][2] * acc[i][2] + acc[i][3] * acc[i][3];
        #pragma unroll
        for (int off = 8; off > 0; off >>= 1) {
            s  += __shfl_down(s,  off, 16);
            ss += __shfl_down(ss, off, 16);
        }
        if (wt == 0) {
            atomicAdd(&ws[o], s);
            atomicAdd(&ws[COUT + o], ss);
        }
    }
}

// ---------------------------------------------------------------------------
// Kernel 2: fold sums -> per-channel scale/shift
// ---------------------------------------------------------------------------
__global__ __launch_bounds__(256) void stats_kernel(
    const float* __restrict__ gamma, const float* __restrict__ beta,
    float* __restrict__ ws)
{
    int t = threadIdx.x;
    if (t < COUT) {
        const float invM = 1.0f / M_;
        float m  = ws[t] * invM;
        float v  = ws[COUT + t] * invM - m * m;
        float rstd = rsqrtf(v + BN_EPS);
        float sc = gamma[t] * rstd;
        ws[2 * COUT + t] = sc;
        ws[3 * COUT + t] = beta[t] - m * sc;
    }
}

// ---------------------------------------------------------------------------
// Kernel 3: in-place normalize of z in d_out (float4, fully coalesced)
// ---------------------------------------------------------------------------
__global__ __launch_bounds__(256) void norm_kernel(
    float* __restrict__ out, const float* __restrict__ ws)
{
    const size_t i = (size_t)blockIdx.x * 256 + threadIdx.x;   // float4 index
    const int c = (int)((i >> 10) % COUT);                     // 1024 float4 per plane
    const float sc = ws[2 * COUT + c];
    const float sh = ws[3 * COUT + c];
    float4 v = ((const float4*)out)[i];
    v.x = fmaf(v.x, sc, sh);
    v.y = fmaf(v.y, sc, sh);
    v.z = fmaf(v.z, sc, sh);
    v.w = fmaf(v.w, sc, sh);
    ((float4*)out)[i] = v;
}

// ---------------------------------------------------------------------------
extern "C" void kernel_launch(void* const* d_in, const int* in_sizes, int n_in,
                              void* d_out, int out_size, void* d_ws, size_t ws_size,
                              hipStream_t stream) {
    const float* x     = (const float*)d_in[0];
    const float* dww   = (const float*)d_in[1];
    const float* pw    = (const float*)d_in[2];
    const float* gamma = (const float*)d_in[3];
    const float* beta  = (const float*)d_in[4];
    float* out = (float*)d_out;
    float* ws  = (float*)d_ws;

    zero_ws<<<1, 384, 0, stream>>>(ws);
    fused_kernel<<<N_ * H_, 256, 0, stream>>>(x, dww, pw, out, ws);
    stats_kernel<<<1, 256, 0, stream>>>(gamma, beta, ws);
    // total float4 elements = 64*192*64*64/4 = 12,582,912 = 49152 * 256
    norm_kernel<<<49152, 256, 0, stream>>>(out, ws);
}

// Round 2
// 836.981 us; speedup vs baseline: 2.0665x; 2.0665x over previous
//
#include <hip/hip_runtime.h>

#define N_    64
#define CIN   192
#define COUT  192
#define H_    64
#define W_    64
#define BN_EPS 1e-5f
#define M_    262144.0f              // N*H*W
#define SYT_STRIDE 200               // bf16 elems per pixel row (192 + 8 pad)

typedef __attribute__((ext_vector_type(8))) short  short8;
typedef __attribute__((ext_vector_type(4))) float  floatx4;

__device__ __forceinline__ unsigned short f2bf(float f) {
    union { float f; unsigned int u; } v; v.f = f;
    unsigned int u = v.u;
    return (unsigned short)((u + 0x7FFFu + ((u >> 16) & 1u)) >> 16);  // RNE
}

// ---------------------------------------------------------------------------
// Kernel 0: zero BN accumulators.
// ws floats: [0..191]=sum [192..383]=sumsq [384..575]=scale [576..767]=shift
// ---------------------------------------------------------------------------
__global__ __launch_bounds__(384) void zero_ws(float* __restrict__ ws) {
    int t = threadIdx.x;
    if (t < 384) ws[t] = 0.f;
}

// ---------------------------------------------------------------------------
// Kernel 1: ReLU + depthwise dilated conv (fp32) -> bf16 LDS (transposed)
//           -> MFMA pointwise GEMM -> z store + BN stats.
// One block per (n, h) row. 256 threads = 4 waves.
// ---------------------------------------------------------------------------
__global__ __launch_bounds__(256, 4) void fused_kernel(
    const float* __restrict__ x, const float* __restrict__ dww,
    const float* __restrict__ pw, float* __restrict__ zout,
    float* __restrict__ ws)
{
    __shared__ float  sdw[CIN * 9];               // 6.9 KB dw weights
    __shared__ unsigned short syT[W_ * SYT_STRIDE]; // 25.6 KB y^T [pix][c] bf16

    const int t = threadIdx.x;
    const int n = blockIdx.x >> 6;
    const int h = blockIdx.x & 63;

    for (int i = t; i < CIN * 9; i += 256) sdw[i] = dww[i];

    // ---- Phase 1: depthwise; thread = (w, cblk), 8 consecutive c per iter ----
    const int  w    = t & 63;
    const int  cblk = t >> 6;                     // 0..3
    const bool wm0  = (w >= 2);
    const bool wm2  = (w <= 61);
    const int  om   = wm0 ? -2 : 0;
    const int  op   = wm2 ?  2 : 0;
    __syncthreads();

    for (int e = 0; e < 6; ++e) {
        const int cb = (cblk + (e << 2)) << 3;    // channel base (multiple of 8)
        float a[8];
        #pragma unroll
        for (int ci = 0; ci < 8; ++ci) {
            const int c = cb + ci;
            const float* xr0 = x + (((size_t)(n * CIN + c)) << 12) + w;
            const float* kw  = &sdw[c * 9];
            float acc = 0.f;
            #pragma unroll
            for (int dh = 0; dh < 3; ++dh) {
                const int hh = h + 2 * dh - 2;
                if ((unsigned)hh < 64u) {         // uniform per block
                    const float* xr = xr0 + (hh << 6);
                    float v0 = fmaxf(xr[om], 0.f);
                    float v1 = fmaxf(xr[0],  0.f);
                    float v2 = fmaxf(xr[op], 0.f);
                    v0 = wm0 ? v0 : 0.f;
                    v2 = wm2 ? v2 : 0.f;
                    acc = fmaf(v0, kw[3 * dh + 0], acc);
                    acc = fmaf(v1, kw[3 * dh + 1], acc);
                    acc = fmaf(v2, kw[3 * dh + 2], acc);
                }
            }
            a[ci] = acc;
        }
        uint4 pk;
        pk.x = (unsigned)f2bf(a[0]) | ((unsigned)f2bf(a[1]) << 16);
        pk.y = (unsigned)f2bf(a[2]) | ((unsigned)f2bf(a[3]) << 16);
        pk.z = (unsigned)f2bf(a[4]) | ((unsigned)f2bf(a[5]) << 16);
        pk.w = (unsigned)f2bf(a[6]) | ((unsigned)f2bf(a[7]) << 16);
        *(uint4*)&syT[w * SYT_STRIDE + cb] = pk;  // 16B aligned (200*2, cb*2)
    }
    __syncthreads();

    // ---- Phase 2: MFMA GEMM. Wave wv: o in [48wv, 48wv+48), all 64 pixels ----
    const int wv   = t >> 6;
    const int lane = t & 63;
    const int l15  = lane & 15;
    const int q    = lane >> 4;                   // quad 0..3
    const int ob   = wv * 48;

    floatx4 acc[3][4];
    #pragma unroll
    for (int mt = 0; mt < 3; ++mt)
        #pragma unroll
        for (int nt = 0; nt < 4; ++nt) acc[mt][nt] = (floatx4)0.f;

    #pragma unroll
    for (int kk = 0; kk < 6; ++kk) {
        const int k0 = kk * 32 + q * 8;           // lane's 8 k-elements

        short8 af[3];
        #pragma unroll
        for (int mt = 0; mt < 3; ++mt) {
            const float4* ap = (const float4*)(pw + (size_t)(ob + mt * 16 + l15) * CIN + k0);
            float4 u = ap[0];
            float4 v = ap[1];
            short8 f;
            f[0] = (short)f2bf(u.x); f[1] = (short)f2bf(u.y);
            f[2] = (short)f2bf(u.z); f[3] = (short)f2bf(u.w);
            f[4] = (short)f2bf(v.x); f[5] = (short)f2bf(v.y);
            f[6] = (short)f2bf(v.z); f[7] = (short)f2bf(v.w);
            af[mt] = f;
        }

        short8 bf[4];
        #pragma unroll
        for (int nt = 0; nt < 4; ++nt)
            bf[nt] = *(const short8*)&syT[(nt * 16 + l15) * SYT_STRIDE + k0];

        #pragma unroll
        for (int mt = 0; mt < 3; ++mt)
            #pragma unroll
            for (int nt = 0; nt < 4; ++nt)
                acc[mt][nt] = __builtin_amdgcn_mfma_f32_16x16x32_bf16(
                    af[mt], bf[nt], acc[mt][nt], 0, 0, 0);
    }

    // ---- Epilogue: store z (D layout: row o = q*4+r, col pix = l15) + stats ----
    const size_t base = (((size_t)n * COUT) << 12) + ((size_t)h << 6);
    #pragma unroll
    for (int mt = 0; mt < 3; ++mt) {
        #pragma unroll
        for (int r = 0; r < 4; ++r) {
            const int o = ob + mt * 16 + q * 4 + r;
            float s = 0.f, ss = 0.f;
            #pragma unroll
            for (int nt = 0; nt < 4; ++nt) {
                const float v = acc[mt][nt][r];
                zout[base + ((size_t)o << 12) + nt * 16 + l15] = v;
                s  += v;
                ss += v * v;
            }
            #pragma unroll
            for (int off = 8; off > 0; off >>= 1) {
                s  += __shfl_down(s,  off, 16);
                ss += __shfl_down(ss, off, 16);
            }
            if (l15 == 0) {
                atomicAdd(&ws[o], s);
                atomicAdd(&ws[COUT + o], ss);
            }
        }
    }
}

// ---------------------------------------------------------------------------
// Kernel 2: fold sums -> per-channel scale/shift
// ---------------------------------------------------------------------------
__global__ __launch_bounds__(256) void stats_kernel(
    const float* __restrict__ gamma, const float* __restrict__ beta,
    float* __restrict__ ws)
{
    int t = threadIdx.x;
    if (t < COUT) {
        const float invM = 1.0f / M_;
        float m    = ws[t] * invM;
        float v    = ws[COUT + t] * invM - m * m;
        float rstd = rsqrtf(v + BN_EPS);
        float sc   = gamma[t] * rstd;
        ws[2 * COUT + t] = sc;
        ws[3 * COUT + t] = beta[t] - m * sc;
    }
}

// ---------------------------------------------------------------------------
// Kernel 3: in-place normalize (float4, coalesced)
// ---------------------------------------------------------------------------
__global__ __launch_bounds__(256) void norm_kernel(
    float* __restrict__ out, const float* __restrict__ ws)
{
    const size_t i = (size_t)blockIdx.x * 256 + threadIdx.x;   // float4 index
    const int c = (int)((i >> 10) % COUT);                     // 1024 float4/plane
    const float sc = ws[2 * COUT + c];
    const float sh = ws[3 * COUT + c];
    float4 v = ((const float4*)out)[i];
    v.x = fmaf(v.x, sc, sh);
    v.y = fmaf(v.y, sc, sh);
    v.z = fmaf(v.z, sc, sh);
    v.w = fmaf(v.w, sc, sh);
    ((float4*)out)[i] = v;
}

// ---------------------------------------------------------------------------
extern "C" void kernel_launch(void* const* d_in, const int* in_sizes, int n_in,
                              void* d_out, int out_size, void* d_ws, size_t ws_size,
                              hipStream_t stream) {
    const float* x     = (const float*)d_in[0];
    const float* dww   = (const float*)d_in[1];
    const float* pw    = (const float*)d_in[2];
    const float* gamma = (const float*)d_in[3];
    const float* beta  = (const float*)d_in[4];
    float* out = (float*)d_out;
    float* ws  = (float*)d_ws;

    zero_ws<<<1, 384, 0, stream>>>(ws);
    fused_kernel<<<N_ * H_, 256, 0, stream>>>(x, dww, pw, out, ws);
    stats_kernel<<<1, 256, 0, stream>>>(gamma, beta, ws);
    norm_kernel<<<49152, 256, 0, stream>>>(out, ws);   // 12,582,912 float4
}